// Round 17
// baseline (311.193 us; speedup 1.0000x reference)
//
#include <hip/hip_runtime.h>

typedef __attribute__((ext_vector_type(4))) float f32x4;
typedef __attribute__((ext_vector_type(8))) short s16x8;
typedef __attribute__((ext_vector_type(2))) unsigned int u32x2;
typedef __attribute__((ext_vector_type(4))) unsigned int u32x4;

#define LOG2E 1.44269504088896340736f

__device__ inline unsigned short f2b(float f) {
  unsigned int u = __float_as_uint(f);
  unsigned int r = (u + 0x7FFFu + ((u >> 16) & 1u)) >> 16;
  return (unsigned short)r;
}

__device__ inline unsigned int cvtpk_bf16(float lo, float hi) {
  unsigned int r;
  asm("v_cvt_pk_bf16_f32 %0, %1, %2" : "=v"(r) : "v"(lo), "v"(hi));
  return r;
}

__device__ inline void gload_lds16(const unsigned short* g, unsigned short* l) {
  __builtin_amdgcn_global_load_lds(
      (const __attribute__((address_space(1))) unsigned int*)g,
      (__attribute__((address_space(3))) unsigned int*)l, 16, 0, 0);
}

#define MFMA16(a, b, c) __builtin_amdgcn_mfma_f32_16x16x32_bf16((a), (b), (c), 0, 0, 0)

// ---------------- K1: w = sum_{t<=task} B[t] @ A[t]  (fp32), K and V fused ----
__global__ __launch_bounds__(256) void lora_merge(const float* __restrict__ A_k,
                                                  const float* __restrict__ B_k,
                                                  const float* __restrict__ A_v,
                                                  const float* __restrict__ B_v,
                                                  float* __restrict__ wk,
                                                  float* __restrict__ wv,
                                                  const int* __restrict__ taskp) {
  const float* A_ = blockIdx.y ? A_v : A_k;
  const float* B_ = blockIdx.y ? B_v : B_k;
  float* Wd = blockIdx.y ? wv : wk;
  __shared__ float Bs[64][65];
  __shared__ float As[64][65];
  const int tile = blockIdx.x;
  const int c0 = (tile >> 4) * 64, d0 = (tile & 15) * 64;
  const int tid = threadIdx.x;
  const int tx = tid & 15, ty = tid >> 4;
  const int T = *taskp + 1;
  float acc[4][4] = {};
  const int r = tid >> 2, cb = (tid & 3) * 16;
  for (int t = 0; t < T; ++t) {
    __syncthreads();
    const float* srcB = B_ + (size_t)t * 65536 + (size_t)(c0 + r) * 64 + cb;
    const float* srcA = A_ + (size_t)t * 65536 + (size_t)r * 1024 + d0 + cb;
#pragma unroll
    for (int j = 0; j < 16; j += 4) {
      f32x4 vb = *(const f32x4*)(srcB + j);
      Bs[r][cb + j] = vb.x; Bs[r][cb + j + 1] = vb.y;
      Bs[r][cb + j + 2] = vb.z; Bs[r][cb + j + 3] = vb.w;
      f32x4 va = *(const f32x4*)(srcA + j);
      As[r][cb + j] = va.x; As[r][cb + j + 1] = va.y;
      As[r][cb + j + 2] = va.z; As[r][cb + j + 3] = va.w;
    }
    __syncthreads();
#pragma unroll 8
    for (int rr = 0; rr < 64; ++rr) {
      float bv[4], av[4];
#pragma unroll
      for (int i = 0; i < 4; ++i) bv[i] = Bs[ty * 4 + i][rr];
#pragma unroll
      for (int j = 0; j < 4; ++j) av[j] = As[rr][tx * 4 + j];
#pragma unroll
      for (int i = 0; i < 4; ++i)
#pragma unroll
        for (int j = 0; j < 4; ++j) acc[i][j] += bv[i] * av[j];
    }
  }
#pragma unroll
  for (int i = 0; i < 4; ++i)
#pragma unroll
    for (int j = 0; j < 4; ++j)
      Wd[(size_t)(c0 + ty * 4 + i) * 1024 + d0 + tx * 4 + j] = acc[i][j];
}

// ---- fused prep: x -> xb (4194304 v4), Wproj -> Wp (262144 v4), Wc build (786432 v4) ----
__global__ void prep_all(const float* __restrict__ x, const float* __restrict__ Wproj,
                         const float* __restrict__ Wqkv, const float* __restrict__ wk,
                         const float* __restrict__ wv, unsigned short* __restrict__ xb,
                         unsigned short* __restrict__ Wp, unsigned short* __restrict__ Wc) {
  int i = blockIdx.x * 256 + threadIdx.x;
  f32x4 v;
  unsigned short* dst;
  int idx;
  if (i < 4194304) {
    idx = i; dst = xb;
    v = ((const f32x4*)x)[idx];
  } else if (i < 4456448) {
    idx = i - 4194304; dst = Wp;
    v = ((const f32x4*)Wproj)[idx];
  } else {
    idx = i - 4456448;  // < 786432
    dst = Wc;
    int e = idx * 4;
    v = *(const f32x4*)(Wqkv + e);
    int row = e >> 10;
    if (row >= 2048) {
      f32x4 d = *(const f32x4*)(wv + (e - 2097152));
      v = v + d;
    } else if (row >= 1024) {
      f32x4 d = *(const f32x4*)(wk + (e - 1048576));
      v = v + d;
    }
  }
  unsigned short o0 = f2b(v.x), o1 = f2b(v.y), o2 = f2b(v.z), o3 = f2b(v.w);
  unsigned long long pack = (unsigned long long)o0 | ((unsigned long long)o1 << 16) |
                            ((unsigned long long)o2 << 32) | ((unsigned long long)o3 << 48);
  ((unsigned long long*)dst)[idx] = pack;
}

// ---------------- GEMM 256x256, BK=64, 8-phase, conflict-free LDS swizzle (R16) -------
template <int OUT_BF16, int ADD_BIAS, int VFUSE>
__global__ __launch_bounds__(512, 1) void gemm256(const unsigned short* __restrict__ A,
                                                  const unsigned short* __restrict__ B,
                                                  void* __restrict__ Cout,
                                                  const float* __restrict__ bias,
                                                  unsigned short* __restrict__ Vt,
                                                  int M, int N, int K) {
  __shared__ unsigned short SM[65536];   // 128 KB; epilogue reuses as T32
  const int tid = threadIdx.x;
  const int w = tid >> 6, l = tid & 63;
  const int lr = l & 15, lg = l >> 4;
  const int wm = w >> 2, wn = w & 3;

  // T1 XCD swizzle (nwg % 8 == 0 for both call sites)
  const int lin = blockIdx.y * gridDim.x + blockIdx.x;
  const int cpx = (gridDim.x * gridDim.y) >> 3;
  const int s = (lin & 7) * cpx + (lin >> 3);
  const int bx = s % gridDim.x, by = s / gridDim.x;

  // staging: row tid>>2 (0..127), global k-chunk (tid&3)^((tid>>3)&3)
  const int r_st = tid >> 2;
  const int k_st = ((tid & 3) ^ ((tid >> 3) & 3)) << 3;
  const unsigned short* gA0 = A + (size_t)(by * 256 + r_st) * K + k_st;
  const unsigned short* gA1 = A + (size_t)(by * 256 + 128 + r_st) * K + k_st;
  const unsigned short* gB0 = B + (size_t)(bx * 256 + r_st) * K + k_st;
  const unsigned short* gB1 = B + (size_t)(bx * 256 + 128 + r_st) * K + k_st;
  const int wb = w * 512;

  // conflict-free fragment read (R9 mapping)
  const int fs = lr * 32 + ((lg ^ ((lr >> 1) & 3)) << 3);
  const int A0 = wm * 8192;                  // + bb*16384
  const int B0 = 32768 + (wn >> 1) * 8192;   // + bb*16384
  const int nb = (wn & 1) * 4;

  f32x4 acc[8][4] = {};
  const int NT2 = K >> 7;   // iterations over K-tile pairs

#define STA(bb, kt, kk)                                                          \
  gload_lds16(gA0 + (kt) * 64 + (kk) * 32, &SM[(bb) * 16384 + (kk) * 4096 + wb]); \
  gload_lds16(gA1 + (kt) * 64 + (kk) * 32, &SM[(bb) * 16384 + 8192 + (kk) * 4096 + wb]);
#define STB(bb, kt, kk)                                                                   \
  gload_lds16(gB0 + (kt) * 64 + (kk) * 32, &SM[32768 + (bb) * 16384 + (kk) * 4096 + wb]); \
  gload_lds16(gB1 + (kt) * 64 + (kk) * 32, &SM[32768 + (bb) * 16384 + 8192 + (kk) * 4096 + wb]);
#define PH_GATE                                            \
  __builtin_amdgcn_s_barrier();                            \
  asm volatile("s_waitcnt lgkmcnt(0)" ::: "memory");       \
  __builtin_amdgcn_sched_barrier(0);                       \
  __builtin_amdgcn_s_setprio(1);
#define PH_END                                             \
  __builtin_amdgcn_s_setprio(0);                           \
  __builtin_amdgcn_sched_barrier(0);                       \
  __builtin_amdgcn_s_barrier();
#define PH_END_VM                                          \
  __builtin_amdgcn_s_setprio(0);                           \
  __builtin_amdgcn_sched_barrier(0);                       \
  asm volatile("s_waitcnt vmcnt(6)" ::: "memory");         \
  __builtin_amdgcn_s_barrier();                            \
  __builtin_amdgcn_sched_barrier(0);

  // prologue: kt0 fully (4 chunk-pairs), kt1 3/4
  STA(0, 0, 0); STB(0, 0, 0); STA(0, 0, 1); STB(0, 0, 1);
  STA(1, 1, 0); STB(1, 1, 0); STA(1, 1, 1);
  asm volatile("s_waitcnt vmcnt(6)" ::: "memory");
  __builtin_amdgcn_s_barrier();
  __builtin_amdgcn_sched_barrier(0);

  for (int it = 0; it < NT2; ++it) {
    const int kt1 = 2 * it + 1;
    const int st2 = (it < NT2 - 1) ? 2 * it + 2 : 2 * it;      // even -> buf0
    const int st3 = (it < NT2 - 1) ? 2 * it + 3 : 2 * it + 1;  // odd  -> buf1
    s16x8 af[8], bf[2];
    // ---- ph1: kt0 k0, n0-1 ----
#pragma unroll
    for (int m = 0; m < 8; ++m) af[m] = *(const s16x8*)&SM[A0 + m * 512 + fs];
#pragma unroll
    for (int j = 0; j < 2; ++j) bf[j] = *(const s16x8*)&SM[B0 + (nb + j) * 512 + fs];
    STB(1, kt1, 1);
    PH_GATE
#pragma unroll
    for (int m = 0; m < 8; ++m)
#pragma unroll
      for (int j = 0; j < 2; ++j) acc[m][j] = MFMA16(af[m], bf[j], acc[m][j]);
    PH_END
    // ---- ph2: kt0 k0, n2-3 ----
#pragma unroll
    for (int j = 0; j < 2; ++j) bf[j] = *(const s16x8*)&SM[B0 + (nb + 2 + j) * 512 + fs];
    STA(0, st2, 0);
    PH_GATE
#pragma unroll
    for (int m = 0; m < 8; ++m)
#pragma unroll
      for (int j = 0; j < 2; ++j) acc[m][2 + j] = MFMA16(af[m], bf[j], acc[m][2 + j]);
    PH_END
    // ---- ph3: kt0 k1, n0-1 ----
#pragma unroll
    for (int m = 0; m < 8; ++m) af[m] = *(const s16x8*)&SM[A0 + 4096 + m * 512 + fs];
#pragma unroll
    for (int j = 0; j < 2; ++j) bf[j] = *(const s16x8*)&SM[B0 + 4096 + (nb + j) * 512 + fs];
    STB(0, st2, 0);
    PH_GATE
#pragma unroll
    for (int m = 0; m < 8; ++m)
#pragma unroll
      for (int j = 0; j < 2; ++j) acc[m][j] = MFMA16(af[m], bf[j], acc[m][j]);
    PH_END
    // ---- ph4: kt0 k1, n2-3 ; vmcnt(6) drains kt1 ----
#pragma unroll
    for (int j = 0; j < 2; ++j) bf[j] = *(const s16x8*)&SM[B0 + 4096 + (nb + 2 + j) * 512 + fs];
    STA(0, st2, 1);
    PH_GATE
#pragma unroll
    for (int m = 0; m < 8; ++m)
#pragma unroll
      for (int j = 0; j < 2; ++j) acc[m][2 + j] = MFMA16(af[m], bf[j], acc[m][2 + j]);
    PH_END_VM
    // ---- ph5: kt1 k0, n0-1 (buffer 1) ----
#pragma unroll
    for (int m = 0; m < 8; ++m) af[m] = *(const s16x8*)&SM[16384 + A0 + m * 512 + fs];
#pragma unroll
    for (int j = 0; j < 2; ++j) bf[j] = *(const s16x8*)&SM[16384 + B0 + (nb + j) * 512 + fs];
    STB(0, st2, 1);
    PH_GATE
#pragma unroll
    for (int m = 0; m < 8; ++m)
#pragma unroll
      for (int j = 0; j < 2; ++j) acc[m][j] = MFMA16(af[m], bf[j], acc[m][j]);
    PH_END
    // ---- ph6: kt1 k0, n2-3 ----
#pragma unroll
    for (int j = 0; j < 2; ++j) bf[j] = *(const s16x8*)&SM[16384 + B0 + (nb + 2 + j) * 512 + fs];
    STA(1, st3, 0);
    PH_GATE
#pragma unroll
    for (int m = 0; m < 8; ++m)
#pragma unroll
      for (int j = 0; j < 2; ++j) acc[m][2 + j] = MFMA16(af[m], bf[j], acc[m][2 + j]);
    PH_END
    // ---- ph7: kt1 k1, n0-1 ----
#pragma unroll
    for (int m = 0; m < 8; ++m) af[m] = *(const s16x8*)&SM[16384 + A0 + 4096 + m * 512 + fs];
#pragma unroll
    for (int j = 0; j < 2; ++j) bf[j] = *(const s16x8*)&SM[16384 + B0 + 4096 + (nb + j) * 512 + fs];
    STB(1, st3, 0);
    PH_GATE
#pragma unroll
    for (int m = 0; m < 8; ++m)
#pragma unroll
      for (int j = 0; j < 2; ++j) acc[m][j] = MFMA16(af[m], bf[j], acc[m][j]);
    PH_END
    // ---- ph8: kt1 k1, n2-3 ; vmcnt(6) drains kt2 ----
#pragma unroll
    for (int j = 0; j < 2; ++j) bf[j] = *(const s16x8*)&SM[16384 + B0 + 4096 + (nb + 2 + j) * 512 + fs];
    STA(1, st3, 1);
    PH_GATE
#pragma unroll
    for (int m = 0; m < 8; ++m)
#pragma unroll
      for (int j = 0; j < 2; ++j) acc[m][2 + j] = MFMA16(af[m], bf[j], acc[m][2 + j]);
    PH_END_VM
  }

  const int crow0 = by * 256 + wm * 128;
  const int ccol0 = bx * 256 + wn * 64;

  if (VFUSE) {
    unsigned short* Cq = (unsigned short*)Cout;   // Q base; K = Cq + 16777216
    if (bx < 8) {
      unsigned short* Cb = Cq + ((size_t)((ccol0 >> 10) & 1)) * 16777216;
#pragma unroll
      for (int m = 0; m < 8; ++m)
#pragma unroll
        for (int n = 0; n < 4; ++n)
#pragma unroll
          for (int rr = 0; rr < 4; ++rr) {
            int row = crow0 + m * 16 + lg * 4 + rr;
            int col = (ccol0 + n * 16 + lr) & 1023;
            Cb[(size_t)row * 1024 + col] = f2b(acc[m][n][rr]);
          }
    } else {
      // V-tile: transpose via LDS. Drain in-flight gload_lds DMAs first!
      asm volatile("s_waitcnt vmcnt(0)" ::: "memory");
      __syncthreads();
      unsigned int* T32 = (unsigned int*)SM;   // [lcol=256][pitch 68 u32] = 69632 B
      const int h0 = (bx - 8) * 4;
      const int bb = by >> 2;
      const int n_base = (by & 3) * 256;
#pragma unroll
      for (int hf = 0; hf < 2; ++hf) {
        if (wm == hf) {
#pragma unroll
          for (int m = 0; m < 8; ++m)
#pragma unroll
            for (int n = 0; n < 4; ++n) {
              int lcol = wn * 64 + n * 16 + lr;
              u32x2 pk;
              pk.x = (unsigned int)f2b(acc[m][n][0]) | ((unsigned int)f2b(acc[m][n][1]) << 16);
              pk.y = (unsigned int)f2b(acc[m][n][2]) | ((unsigned int)f2b(acc[m][n][3]) << 16);
              *(u32x2*)&T32[lcol * 68 + m * 8 + lg * 2] = pk;
            }
        }
        __syncthreads();
#pragma unroll
        for (int p = 0; p < 8; ++p) {
          int slot2 = p * 512 + tid;
          int d256 = slot2 >> 4;
          int ncq = (slot2 & 15) * 4;            // u32 units (= 8 bf16)
          u32x4 v = *(const u32x4*)&T32[d256 * 68 + ncq];
          int hloc = d256 >> 6, d = d256 & 63;
          size_t dst = (size_t)(bb * 16 + h0 + hloc) * 65536 + (size_t)d * 1024 +
                       (n_base + hf * 128 + ncq * 2);
          *(u32x4*)&Vt[dst] = v;
        }
        __syncthreads();
      }
    }
  } else if (OUT_BF16) {
    unsigned short* C = (unsigned short*)Cout;
#pragma unroll
    for (int m = 0; m < 8; ++m)
#pragma unroll
      for (int n = 0; n < 4; ++n)
#pragma unroll
        for (int rr = 0; rr < 4; ++rr) {
          int row = crow0 + m * 16 + lg * 4 + rr;
          int col = ccol0 + n * 16 + lr;
          C[(size_t)row * N + col] = f2b(acc[m][n][rr]);
        }
  } else {
    float* C = (float*)Cout;
#pragma unroll
    for (int m = 0; m < 8; ++m)
#pragma unroll
      for (int n = 0; n < 4; ++n)
#pragma unroll
        for (int rr = 0; rr < 4; ++rr) {
          int row = crow0 + m * 16 + lg * 4 + rr;
          int col = ccol0 + n * 16 + lr;
          float b = ADD_BIAS ? bias[col] : 0.f;
          C[(size_t)row * N + col] = acc[m][n][rr] + b;
        }
  }
#undef STA
#undef STB
#undef PH_GATE
#undef PH_END
#undef PH_END_VM
}

// ---------------- flash attention: 2 q-groups, fragment reuse, SHARED Ps stripe -------
// Ps is per-wave (not per-(wave,qg)): qg0 round-trips P through the stripe into regs,
// then qg1 reuses the SAME stripe (same-wave DS ops are in-order; must-alias + explicit
// sched_barrier(0) keeps the compiler from reordering the qg1 writes above qg0 reads).
// LDS 69.6KB -> 51.2KB => 3 blocks/CU (was 2): +50% TLP for this latency-bound kernel.
__global__ __launch_bounds__(512) void attn_fwd(const unsigned short* __restrict__ Qb,
                                                const unsigned short* __restrict__ Kb,
                                                const unsigned short* __restrict__ vT,
                                                unsigned short* __restrict__ out) {
  const int tid = threadIdx.x;
  const int w = tid >> 6, l = tid & 63;
  const int lr = l & 15, lg = l >> 4;
  const int bid = blockIdx.x;
  const int g = (bid & 7) * 32 + (bid >> 5);   // (b,h) group 0..255
  const int qt2 = (bid >> 3) & 3;              // q-quarter 0..3
  const int b = g >> 4, h = g & 15;

  __shared__ unsigned short Ks[2][4096];
  __shared__ unsigned short Vs[2][4096];
  __shared__ unsigned int Ps[8][576];   // per-wave stripe, pitch 36 u32 (qg-serial)

  const size_t base = (size_t)b * 1048576 + h * 64;
  const unsigned short* Qp = Qb + base;
  const unsigned short* Kp = Kb + base;
  const unsigned short* vTp = vT + (size_t)(b * 16 + h) * 65536;

  const float SSCALE = 0.125f * LOG2E;
  const int qb = qt2 * 256;
  s16x8 qf[2][2];
#pragma unroll
  for (int qg = 0; qg < 2; ++qg) {
    const int qrow = qb + qg * 128 + w * 16 + lr;
    qf[qg][0] = *(const s16x8*)(Qp + (size_t)qrow * 1024 + lg * 8);
    qf[qg][1] = *(const s16x8*)(Qp + (size_t)qrow * 1024 + 32 + lg * 8);
#pragma unroll
    for (int kk = 0; kk < 2; ++kk)
#pragma unroll
      for (int j = 0; j < 8; ++j) {
        float f = __uint_as_float(((unsigned int)(unsigned short)qf[qg][kk][j]) << 16) * SSCALE;
        qf[qg][kk][j] = (short)f2b(f);
      }
  }

  s16x8 ONES;
#pragma unroll
  for (int j = 0; j < 8; ++j) ONES[j] = (short)0x3F80;  // bf16 1.0

  f32x4 o[2][4] = {};
  f32x4 o4[2] = {};

  const int srow = tid >> 3;
  const int csrc = (tid & 7) ^ (srow & 7);

  gload_lds16(Kp + (size_t)srow * 1024 + csrc * 8, &Ks[0][w * 512]);
  gload_lds16(vTp + (size_t)srow * 1024 + csrc * 8, &Vs[0][w * 512]);
  __syncthreads();

  for (int t = 0; t < 16; ++t) {
    const int cur = t & 1;
    if (t < 15) {
      const int kv1 = (t + 1) * 64;
      gload_lds16(Kp + (size_t)(kv1 + srow) * 1024 + csrc * 8, &Ks[cur ^ 1][w * 512]);
      gload_lds16(vTp + (size_t)srow * 1024 + kv1 + csrc * 8, &Vs[cur ^ 1][w * 512]);
    }
    const unsigned short* Kb_ = &Ks[cur][0];
    const unsigned short* Vb = &Vs[cur][0];

    // QK^T for both q-groups; each kf read feeds 2 MFMAs
    f32x4 sc[2][4] = {};
    __builtin_amdgcn_s_setprio(1);
#pragma unroll
    for (int kk = 0; kk < 2; ++kk)
#pragma unroll
      for (int tt = 0; tt < 4; ++tt) {
        int krow = tt * 16 + lr;
        s16x8 kf = *(const s16x8*)&Kb_[krow * 64 + ((((kk * 32 + lg * 8) >> 3) ^ (krow & 7)) << 3)];
        sc[0][tt] = MFMA16(kf, qf[0][kk], sc[0][tt]);
        sc[1][tt] = MFMA16(kf, qf[1][kk], sc[1][tt]);
      }
    __builtin_amdgcn_s_setprio(0);

    // softmax + P round-trip, qg-serial through the shared per-wave stripe
    s16x8 pf[2][2];
#pragma unroll
    for (int qg = 0; qg < 2; ++qg) {
      unsigned int* Pw = &Ps[w][0];
#pragma unroll
      for (int tt = 0; tt < 4; ++tt) {
        float p0 = exp2f(sc[qg][tt][0]);
        float p1 = exp2f(sc[qg][tt][1]);
        float p2 = exp2f(sc[qg][tt][2]);
        float p3 = exp2f(sc[qg][tt][3]);
        u32x2 pk;
        pk.x = cvtpk_bf16(p0, p1);
        pk.y = cvtpk_bf16(p2, p3);
        *(u32x2*)&Pw[lr * 36 + tt * 8 + lg * 2] = pk;
      }
      __builtin_amdgcn_sched_barrier(0);
#pragma unroll
      for (int kk = 0; kk < 2; ++kk) {
        u32x4 pu = *(const u32x4*)&Pw[lr * 36 + kk * 16 + lg * 4];
        pf[qg][kk] = __builtin_bit_cast(s16x8, pu);
      }
      __builtin_amdgcn_sched_barrier(0);
    }

    // PV + ones-denominator; each vf read feeds 2 MFMAs
#pragma unroll
    for (int kk = 0; kk < 2; ++kk) {
      __builtin_amdgcn_s_setprio(1);
      o4[0] = MFMA16(pf[0][kk], ONES, o4[0]);
      o4[1] = MFMA16(pf[1][kk], ONES, o4[1]);
#pragma unroll
      for (int dt = 0; dt < 4; ++dt) {
        int vrow = dt * 16 + lr;
        s16x8 vf = *(const s16x8*)&Vb[vrow * 64 + ((((kk * 32 + lg * 8) >> 3) ^ (vrow & 7)) << 3)];
        o[0][dt] = MFMA16(pf[0][kk], vf, o[0][dt]);
        o[1][dt] = MFMA16(pf[1][kk], vf, o[1][dt]);
      }
      __builtin_amdgcn_s_setprio(0);
    }
    __syncthreads();
  }

#pragma unroll
  for (int qg = 0; qg < 2; ++qg) {
    f32x4 lq;
#pragma unroll
    for (int rr = 0; rr < 4; ++rr) lq[rr] = 1.f / o4[qg][rr];
    const size_t orow0 = (size_t)b * 1024 + qb + qg * 128 + w * 16;
#pragma unroll
    for (int dt = 0; dt < 4; ++dt)
#pragma unroll
      for (int rr = 0; rr < 4; ++rr)
        out[(orow0 + lg * 4 + rr) * 1024 + h * 64 + dt * 16 + lr] = f2b(o[qg][dt][rr] * lq[rr]);
  }
}

extern "C" void kernel_launch(void* const* d_in, const int* in_sizes, int n_in,
                              void* d_out, int out_size, void* d_ws, size_t ws_size,
                              hipStream_t stream) {
  const float* x = (const float*)d_in[0];
  const float* Wqkv = (const float*)d_in[1];
  const float* Wproj = (const float*)d_in[2];
  const float* bproj = (const float*)d_in[3];
  const float* A_k = (const float*)d_in[4];
  const float* B_k = (const float*)d_in[5];
  const float* A_v = (const float*)d_in[6];
  const float* B_v = (const float*)d_in[7];
  const int* task = (const int*)d_in[8];

  char* ws = (char*)d_ws;
  float* wk = (float*)ws;                                       // 4 MB
  float* wv = (float*)(ws + (4ull << 20));                      // 4 MB
  unsigned short* xb = (unsigned short*)(ws + (8ull << 20));    // 32 MB
  unsigned short* Wc = (unsigned short*)(ws + (40ull << 20));   // 6 MB
  unsigned short* Wp = (unsigned short*)(ws + (46ull << 20));   // 2 MB
  unsigned short* Qb = (unsigned short*)(ws + (48ull << 20));   // 32 MB (Kb = Qb+16M elems)
  unsigned short* Kb = (unsigned short*)(ws + (80ull << 20));   // 32 MB
  unsigned short* vT = (unsigned short*)(ws + (112ull << 20));  // 32 MB
  unsigned short* ao = (unsigned short*)(ws + (144ull << 20));  // 32 MB

  lora_merge<<<dim3(256, 2), 256, 0, stream>>>(A_k, B_k, A_v, B_v, wk, wv, task);
  prep_all<<<20480, 256, 0, stream>>>(x, Wproj, Wqkv, wk, wv, xb, Wp, Wc);
  gemm256<1, 0, 1><<<dim3(12, 64), 512, 0, stream>>>(xb, Wc, Qb, nullptr, vT, 16384, 3072, 1024);
  attn_fwd<<<1024, 512, 0, stream>>>(Qb, Kb, vT, ao);
  gemm256<0, 1, 0><<<dim3(4, 64), 512, 0, stream>>>(ao, Wp, d_out, bproj, nullptr, 16384, 1024, 1024);
}

// Round 18
// 299.138 us; speedup vs baseline: 1.0403x; 1.0403x over previous
//
#include <hip/hip_runtime.h>

typedef __attribute__((ext_vector_type(4))) float f32x4;
typedef __attribute__((ext_vector_type(8))) short s16x8;
typedef __attribute__((ext_vector_type(2))) unsigned int u32x2;
typedef __attribute__((ext_vector_type(4))) unsigned int u32x4;

#define LOG2E 1.44269504088896340736f

__device__ inline unsigned short f2b(float f) {
  unsigned int u = __float_as_uint(f);
  unsigned int r = (u + 0x7FFFu + ((u >> 16) & 1u)) >> 16;
  return (unsigned short)r;
}

__device__ inline unsigned int cvtpk_bf16(float lo, float hi) {
  unsigned int r;
  asm("v_cvt_pk_bf16_f32 %0, %1, %2" : "=v"(r) : "v"(lo), "v"(hi));
  return r;
}

__device__ inline void gload_lds16(const unsigned short* g, unsigned short* l) {
  __builtin_amdgcn_global_load_lds(
      (const __attribute__((address_space(1))) unsigned int*)g,
      (__attribute__((address_space(3))) unsigned int*)l, 16, 0, 0);
}

#define MFMA16(a, b, c) __builtin_amdgcn_mfma_f32_16x16x32_bf16((a), (b), (c), 0, 0, 0)

// ---- fused: lora_merge (blocks 0..511) || x->xb, Wproj->Wp cvt (blocks 512..17919) ----
// Only Wc depends on wk/wv; it is built in the separate build_wc kernel afterwards.
__global__ __launch_bounds__(256) void lora_and_cvt(const float* __restrict__ A_k,
                                                    const float* __restrict__ B_k,
                                                    const float* __restrict__ A_v,
                                                    const float* __restrict__ B_v,
                                                    float* __restrict__ wk,
                                                    float* __restrict__ wv,
                                                    const int* __restrict__ taskp,
                                                    const float* __restrict__ x,
                                                    const float* __restrict__ Wproj,
                                                    unsigned short* __restrict__ xb,
                                                    unsigned short* __restrict__ Wp) {
  __shared__ float Bs[64][65];
  __shared__ float As[64][65];
  const int blk = blockIdx.x;
  const int tid = threadIdx.x;
  if (blk >= 512) {
    // streaming conversion: i over [0, 4456448) v4 elements
    int i = (blk - 512) * 256 + tid;
    const float* src;
    unsigned short* dst;
    int idx;
    if (i < 4194304) { idx = i; src = x; dst = xb; }
    else { idx = i - 4194304; src = Wproj; dst = Wp; }   // idx < 262144
    f32x4 v = ((const f32x4*)src)[idx];
    unsigned short o0 = f2b(v.x), o1 = f2b(v.y), o2 = f2b(v.z), o3 = f2b(v.w);
    unsigned long long pack = (unsigned long long)o0 | ((unsigned long long)o1 << 16) |
                              ((unsigned long long)o2 << 32) | ((unsigned long long)o3 << 48);
    ((unsigned long long*)dst)[idx] = pack;
    return;
  }
  // lora: w = sum_{t<=task} B[t] @ A[t]
  const int kv = (blk >> 8) & 1;
  const float* A_ = kv ? A_v : A_k;
  const float* B_ = kv ? B_v : B_k;
  float* Wd = kv ? wv : wk;
  const int tile = blk & 255;
  const int c0 = (tile >> 4) * 64, d0 = (tile & 15) * 64;
  const int tx = tid & 15, ty = tid >> 4;
  const int T = *taskp + 1;
  float acc[4][4] = {};
  const int r = tid >> 2, cb = (tid & 3) * 16;
  for (int t = 0; t < T; ++t) {
    __syncthreads();
    const float* srcB = B_ + (size_t)t * 65536 + (size_t)(c0 + r) * 64 + cb;
    const float* srcA = A_ + (size_t)t * 65536 + (size_t)r * 1024 + d0 + cb;
#pragma unroll
    for (int j = 0; j < 16; j += 4) {
      f32x4 vb = *(const f32x4*)(srcB + j);
      Bs[r][cb + j] = vb.x; Bs[r][cb + j + 1] = vb.y;
      Bs[r][cb + j + 2] = vb.z; Bs[r][cb + j + 3] = vb.w;
      f32x4 va = *(const f32x4*)(srcA + j);
      As[r][cb + j] = va.x; As[r][cb + j + 1] = va.y;
      As[r][cb + j + 2] = va.z; As[r][cb + j + 3] = va.w;
    }
    __syncthreads();
#pragma unroll 8
    for (int rr = 0; rr < 64; ++rr) {
      float bv[4], av[4];
#pragma unroll
      for (int i2 = 0; i2 < 4; ++i2) bv[i2] = Bs[ty * 4 + i2][rr];
#pragma unroll
      for (int j = 0; j < 4; ++j) av[j] = As[rr][tx * 4 + j];
#pragma unroll
      for (int i2 = 0; i2 < 4; ++i2)
#pragma unroll
        for (int j = 0; j < 4; ++j) acc[i2][j] += bv[i2] * av[j];
    }
  }
#pragma unroll
  for (int i2 = 0; i2 < 4; ++i2)
#pragma unroll
    for (int j = 0; j < 4; ++j)
      Wd[(size_t)(c0 + ty * 4 + i2) * 1024 + d0 + tx * 4 + j] = acc[i2][j];
}

// ---- build Wc[3072][1024] = bf16(W_qkv + [0; wk; wv])  (786432 v4 elems) ----
__global__ void build_wc(const float* __restrict__ Wqkv, const float* __restrict__ wk,
                         const float* __restrict__ wv, unsigned short* __restrict__ Wc) {
  int i = blockIdx.x * 256 + threadIdx.x;
  int e = i * 4;
  f32x4 v = *(const f32x4*)(Wqkv + e);
  int row = e >> 10;
  if (row >= 2048) {
    f32x4 d = *(const f32x4*)(wv + (e - 2097152));
    v = v + d;
  } else if (row >= 1024) {
    f32x4 d = *(const f32x4*)(wk + (e - 1048576));
    v = v + d;
  }
  unsigned short o0 = f2b(v.x), o1 = f2b(v.y), o2 = f2b(v.z), o3 = f2b(v.w);
  unsigned long long pack = (unsigned long long)o0 | ((unsigned long long)o1 << 16) |
                            ((unsigned long long)o2 << 32) | ((unsigned long long)o3 << 48);
  ((unsigned long long*)Wc)[i] = pack;
}

// ---------------- GEMM 256x256, BK=64, 8-phase, conflict-free LDS swizzle (R16) -------
template <int OUT_BF16, int ADD_BIAS, int VFUSE>
__global__ __launch_bounds__(512, 1) void gemm256(const unsigned short* __restrict__ A,
                                                  const unsigned short* __restrict__ B,
                                                  void* __restrict__ Cout,
                                                  const float* __restrict__ bias,
                                                  unsigned short* __restrict__ Vt,
                                                  int M, int N, int K) {
  __shared__ unsigned short SM[65536];   // 128 KB; epilogue reuses as T32
  const int tid = threadIdx.x;
  const int w = tid >> 6, l = tid & 63;
  const int lr = l & 15, lg = l >> 4;
  const int wm = w >> 2, wn = w & 3;

  // T1 XCD swizzle (nwg % 8 == 0 for both call sites)
  const int lin = blockIdx.y * gridDim.x + blockIdx.x;
  const int cpx = (gridDim.x * gridDim.y) >> 3;
  const int s = (lin & 7) * cpx + (lin >> 3);
  const int bx = s % gridDim.x, by = s / gridDim.x;

  // staging: row tid>>2 (0..127), global k-chunk (tid&3)^((tid>>3)&3)
  const int r_st = tid >> 2;
  const int k_st = ((tid & 3) ^ ((tid >> 3) & 3)) << 3;
  const unsigned short* gA0 = A + (size_t)(by * 256 + r_st) * K + k_st;
  const unsigned short* gA1 = A + (size_t)(by * 256 + 128 + r_st) * K + k_st;
  const unsigned short* gB0 = B + (size_t)(bx * 256 + r_st) * K + k_st;
  const unsigned short* gB1 = B + (size_t)(bx * 256 + 128 + r_st) * K + k_st;
  const int wb = w * 512;

  // conflict-free fragment read (R9 mapping)
  const int fs = lr * 32 + ((lg ^ ((lr >> 1) & 3)) << 3);
  const int A0 = wm * 8192;                  // + bb*16384
  const int B0 = 32768 + (wn >> 1) * 8192;   // + bb*16384
  const int nb = (wn & 1) * 4;

  f32x4 acc[8][4] = {};
  const int NT2 = K >> 7;   // iterations over K-tile pairs

#define STA(bb, kt, kk)                                                          \
  gload_lds16(gA0 + (kt) * 64 + (kk) * 32, &SM[(bb) * 16384 + (kk) * 4096 + wb]); \
  gload_lds16(gA1 + (kt) * 64 + (kk) * 32, &SM[(bb) * 16384 + 8192 + (kk) * 4096 + wb]);
#define STB(bb, kt, kk)                                                                   \
  gload_lds16(gB0 + (kt) * 64 + (kk) * 32, &SM[32768 + (bb) * 16384 + (kk) * 4096 + wb]); \
  gload_lds16(gB1 + (kt) * 64 + (kk) * 32, &SM[32768 + (bb) * 16384 + 8192 + (kk) * 4096 + wb]);
#define PH_GATE                                            \
  __builtin_amdgcn_s_barrier();                            \
  asm volatile("s_waitcnt lgkmcnt(0)" ::: "memory");       \
  __builtin_amdgcn_sched_barrier(0);                       \
  __builtin_amdgcn_s_setprio(1);
#define PH_END                                             \
  __builtin_amdgcn_s_setprio(0);                           \
  __builtin_amdgcn_sched_barrier(0);                       \
  __builtin_amdgcn_s_barrier();
#define PH_END_VM                                          \
  __builtin_amdgcn_s_setprio(0);                           \
  __builtin_amdgcn_sched_barrier(0);                       \
  asm volatile("s_waitcnt vmcnt(6)" ::: "memory");         \
  __builtin_amdgcn_s_barrier();                            \
  __builtin_amdgcn_sched_barrier(0);

  // prologue: kt0 fully (4 chunk-pairs), kt1 3/4
  STA(0, 0, 0); STB(0, 0, 0); STA(0, 0, 1); STB(0, 0, 1);
  STA(1, 1, 0); STB(1, 1, 0); STA(1, 1, 1);
  asm volatile("s_waitcnt vmcnt(6)" ::: "memory");
  __builtin_amdgcn_s_barrier();
  __builtin_amdgcn_sched_barrier(0);

  for (int it = 0; it < NT2; ++it) {
    const int kt1 = 2 * it + 1;
    const int st2 = (it < NT2 - 1) ? 2 * it + 2 : 2 * it;      // even -> buf0
    const int st3 = (it < NT2 - 1) ? 2 * it + 3 : 2 * it + 1;  // odd  -> buf1
    s16x8 af[8], bf[2];
    // ---- ph1: kt0 k0, n0-1 ----
#pragma unroll
    for (int m = 0; m < 8; ++m) af[m] = *(const s16x8*)&SM[A0 + m * 512 + fs];
#pragma unroll
    for (int j = 0; j < 2; ++j) bf[j] = *(const s16x8*)&SM[B0 + (nb + j) * 512 + fs];
    STB(1, kt1, 1);
    PH_GATE
#pragma unroll
    for (int m = 0; m < 8; ++m)
#pragma unroll
      for (int j = 0; j < 2; ++j) acc[m][j] = MFMA16(af[m], bf[j], acc[m][j]);
    PH_END
    // ---- ph2: kt0 k0, n2-3 ----
#pragma unroll
    for (int j = 0; j < 2; ++j) bf[j] = *(const s16x8*)&SM[B0 + (nb + 2 + j) * 512 + fs];
    STA(0, st2, 0);
    PH_GATE
#pragma unroll
    for (int m = 0; m < 8; ++m)
#pragma unroll
      for (int j = 0; j < 2; ++j) acc[m][2 + j] = MFMA16(af[m], bf[j], acc[m][2 + j]);
    PH_END
    // ---- ph3: kt0 k1, n0-1 ----
#pragma unroll
    for (int m = 0; m < 8; ++m) af[m] = *(const s16x8*)&SM[A0 + 4096 + m * 512 + fs];
#pragma unroll
    for (int j = 0; j < 2; ++j) bf[j] = *(const s16x8*)&SM[B0 + 4096 + (nb + j) * 512 + fs];
    STB(0, st2, 0);
    PH_GATE
#pragma unroll
    for (int m = 0; m < 8; ++m)
#pragma unroll
      for (int j = 0; j < 2; ++j) acc[m][j] = MFMA16(af[m], bf[j], acc[m][j]);
    PH_END
    // ---- ph4: kt0 k1, n2-3 ; vmcnt(6) drains kt1 ----
#pragma unroll
    for (int j = 0; j < 2; ++j) bf[j] = *(const s16x8*)&SM[B0 + 4096 + (nb + 2 + j) * 512 + fs];
    STA(0, st2, 1);
    PH_GATE
#pragma unroll
    for (int m = 0; m < 8; ++m)
#pragma unroll
      for (int j = 0; j < 2; ++j) acc[m][2 + j] = MFMA16(af[m], bf[j], acc[m][2 + j]);
    PH_END_VM
    // ---- ph5: kt1 k0, n0-1 (buffer 1) ----
#pragma unroll
    for (int m = 0; m < 8; ++m) af[m] = *(const s16x8*)&SM[16384 + A0 + m * 512 + fs];
#pragma unroll
    for (int j = 0; j < 2; ++j) bf[j] = *(const s16x8*)&SM[16384 + B0 + (nb + j) * 512 + fs];
    STB(0, st2, 1);
    PH_GATE
#pragma unroll
    for (int m = 0; m < 8; ++m)
#pragma unroll
      for (int j = 0; j < 2; ++j) acc[m][j] = MFMA16(af[m], bf[j], acc[m][j]);
    PH_END
    // ---- ph6: kt1 k0, n2-3 ----
#pragma unroll
    for (int j = 0; j < 2; ++j) bf[j] = *(const s16x8*)&SM[16384 + B0 + (nb + 2 + j) * 512 + fs];
    STA(1, st3, 0);
    PH_GATE
#pragma unroll
    for (int m = 0; m < 8; ++m)
#pragma unroll
      for (int j = 0; j < 2; ++j) acc[m][2 + j] = MFMA16(af[m], bf[j], acc[m][2 + j]);
    PH_END
    // ---- ph7: kt1 k1, n0-1 ----
#pragma unroll
    for (int m = 0; m < 8; ++m) af[m] = *(const s16x8*)&SM[16384 + A0 + 4096 + m * 512 + fs];
#pragma unroll
    for (int j = 0; j < 2; ++j) bf[j] = *(const s16x8*)&SM[16384 + B0 + 4096 + (nb + j) * 512 + fs];
    STB(1, st3, 0);
    PH_GATE
#pragma unroll
    for (int m = 0; m < 8; ++m)
#pragma unroll
      for (int j = 0; j < 2; ++j) acc[m][j] = MFMA16(af[m], bf[j], acc[m][j]);
    PH_END
    // ---- ph8: kt1 k1, n2-3 ; vmcnt(6) drains kt2 ----
#pragma unroll
    for (int j = 0; j < 2; ++j) bf[j] = *(const s16x8*)&SM[16384 + B0 + 4096 + (nb + 2 + j) * 512 + fs];
    STA(1, st3, 1);
    PH_GATE
#pragma unroll
    for (int m = 0; m < 8; ++m)
#pragma unroll
      for (int j = 0; j < 2; ++j) acc[m][2 + j] = MFMA16(af[m], bf[j], acc[m][2 + j]);
    PH_END_VM
  }

  const int crow0 = by * 256 + wm * 128;
  const int ccol0 = bx * 256 + wn * 64;

  if (VFUSE) {
    unsigned short* Cq = (unsigned short*)Cout;   // Q base; K = Cq + 16777216
    if (bx < 8) {
      unsigned short* Cb = Cq + ((size_t)((ccol0 >> 10) & 1)) * 16777216;
#pragma unroll
      for (int m = 0; m < 8; ++m)
#pragma unroll
        for (int n = 0; n < 4; ++n)
#pragma unroll
          for (int rr = 0; rr < 4; ++rr) {
            int row = crow0 + m * 16 + lg * 4 + rr;
            int col = (ccol0 + n * 16 + lr) & 1023;
            Cb[(size_t)row * 1024 + col] = f2b(acc[m][n][rr]);
          }
    } else {
      // V-tile: transpose via LDS. Drain in-flight gload_lds DMAs first!
      asm volatile("s_waitcnt vmcnt(0)" ::: "memory");
      __syncthreads();
      unsigned int* T32 = (unsigned int*)SM;   // [lcol=256][pitch 68 u32] = 69632 B
      const int h0 = (bx - 8) * 4;
      const int bb = by >> 2;
      const int n_base = (by & 3) * 256;
#pragma unroll
      for (int hf = 0; hf < 2; ++hf) {
        if (wm == hf) {
#pragma unroll
          for (int m = 0; m < 8; ++m)
#pragma unroll
            for (int n = 0; n < 4; ++n) {
              int lcol = wn * 64 + n * 16 + lr;
              u32x2 pk;
              pk.x = (unsigned int)f2b(acc[m][n][0]) | ((unsigned int)f2b(acc[m][n][1]) << 16);
              pk.y = (unsigned int)f2b(acc[m][n][2]) | ((unsigned int)f2b(acc[m][n][3]) << 16);
              *(u32x2*)&T32[lcol * 68 + m * 8 + lg * 2] = pk;
            }
        }
        __syncthreads();
#pragma unroll
        for (int p = 0; p < 8; ++p) {
          int slot2 = p * 512 + tid;
          int d256 = slot2 >> 4;
          int ncq = (slot2 & 15) * 4;            // u32 units (= 8 bf16)
          u32x4 v = *(const u32x4*)&T32[d256 * 68 + ncq];
          int hloc = d256 >> 6, d = d256 & 63;
          size_t dst = (size_t)(bb * 16 + h0 + hloc) * 65536 + (size_t)d * 1024 +
                       (n_base + hf * 128 + ncq * 2);
          *(u32x4*)&Vt[dst] = v;
        }
        __syncthreads();
      }
    }
  } else if (OUT_BF16) {
    unsigned short* C = (unsigned short*)Cout;
#pragma unroll
    for (int m = 0; m < 8; ++m)
#pragma unroll
      for (int n = 0; n < 4; ++n)
#pragma unroll
        for (int rr = 0; rr < 4; ++rr) {
          int row = crow0 + m * 16 + lg * 4 + rr;
          int col = ccol0 + n * 16 + lr;
          C[(size_t)row * N + col] = f2b(acc[m][n][rr]);
        }
  } else {
    float* C = (float*)Cout;
#pragma unroll
    for (int m = 0; m < 8; ++m)
#pragma unroll
      for (int n = 0; n < 4; ++n)
#pragma unroll
        for (int rr = 0; rr < 4; ++rr) {
          int row = crow0 + m * 16 + lg * 4 + rr;
          int col = ccol0 + n * 16 + lr;
          float b = ADD_BIAS ? bias[col] : 0.f;
          C[(size_t)row * N + col] = acc[m][n][rr] + b;
        }
  }
#undef STA
#undef STB
#undef PH_GATE
#undef PH_END
#undef PH_END_VM
}

// ---------------- flash attention: 2 q-groups, fragment reuse, shared Ps stripe -------
__global__ __launch_bounds__(512) void attn_fwd(const unsigned short* __restrict__ Qb,
                                                const unsigned short* __restrict__ Kb,
                                                const unsigned short* __restrict__ vT,
                                                unsigned short* __restrict__ out) {
  const int tid = threadIdx.x;
  const int w = tid >> 6, l = tid & 63;
  const int lr = l & 15, lg = l >> 4;
  const int bid = blockIdx.x;
  const int g = (bid & 7) * 32 + (bid >> 5);   // (b,h) group 0..255
  const int qt2 = (bid >> 3) & 3;              // q-quarter 0..3
  const int b = g >> 4, h = g & 15;

  __shared__ unsigned short Ks[2][4096];
  __shared__ unsigned short Vs[2][4096];
  __shared__ unsigned int Ps[8][576];   // per-wave stripe, pitch 36 u32 (qg-serial)

  const size_t base = (size_t)b * 1048576 + h * 64;
  const unsigned short* Qp = Qb + base;
  const unsigned short* Kp = Kb + base;
  const unsigned short* vTp = vT + (size_t)(b * 16 + h) * 65536;

  const float SSCALE = 0.125f * LOG2E;
  const int qb = qt2 * 256;
  s16x8 qf[2][2];
#pragma unroll
  for (int qg = 0; qg < 2; ++qg) {
    const int qrow = qb + qg * 128 + w * 16 + lr;
    qf[qg][0] = *(const s16x8*)(Qp + (size_t)qrow * 1024 + lg * 8);
    qf[qg][1] = *(const s16x8*)(Qp + (size_t)qrow * 1024 + 32 + lg * 8);
#pragma unroll
    for (int kk = 0; kk < 2; ++kk)
#pragma unroll
      for (int j = 0; j < 8; ++j) {
        float f = __uint_as_float(((unsigned int)(unsigned short)qf[qg][kk][j]) << 16) * SSCALE;
        qf[qg][kk][j] = (short)f2b(f);
      }
  }

  s16x8 ONES;
#pragma unroll
  for (int j = 0; j < 8; ++j) ONES[j] = (short)0x3F80;  // bf16 1.0

  f32x4 o[2][4] = {};
  f32x4 o4[2] = {};

  const int srow = tid >> 3;
  const int csrc = (tid & 7) ^ (srow & 7);

  gload_lds16(Kp + (size_t)srow * 1024 + csrc * 8, &Ks[0][w * 512]);
  gload_lds16(vTp + (size_t)srow * 1024 + csrc * 8, &Vs[0][w * 512]);
  __syncthreads();

  for (int t = 0; t < 16; ++t) {
    const int cur = t & 1;
    if (t < 15) {
      const int kv1 = (t + 1) * 64;
      gload_lds16(Kp + (size_t)(kv1 + srow) * 1024 + csrc * 8, &Ks[cur ^ 1][w * 512]);
      gload_lds16(vTp + (size_t)srow * 1024 + kv1 + csrc * 8, &Vs[cur ^ 1][w * 512]);
    }
    const unsigned short* Kb_ = &Ks[cur][0];
    const unsigned short* Vb = &Vs[cur][0];

    f32x4 sc[2][4] = {};
    __builtin_amdgcn_s_setprio(1);
#pragma unroll
    for (int kk = 0; kk < 2; ++kk)
#pragma unroll
      for (int tt = 0; tt < 4; ++tt) {
        int krow = tt * 16 + lr;
        s16x8 kf = *(const s16x8*)&Kb_[krow * 64 + ((((kk * 32 + lg * 8) >> 3) ^ (krow & 7)) << 3)];
        sc[0][tt] = MFMA16(kf, qf[0][kk], sc[0][tt]);
        sc[1][tt] = MFMA16(kf, qf[1][kk], sc[1][tt]);
      }
    __builtin_amdgcn_s_setprio(0);

    s16x8 pf[2][2];
#pragma unroll
    for (int qg = 0; qg < 2; ++qg) {
      unsigned int* Pw = &Ps[w][0];
#pragma unroll
      for (int tt = 0; tt < 4; ++tt) {
        float p0 = exp2f(sc[qg][tt][0]);
        float p1 = exp2f(sc[qg][tt][1]);
        float p2 = exp2f(sc[qg][tt][2]);
        float p3 = exp2f(sc[qg][tt][3]);
        u32x2 pk;
        pk.x = cvtpk_bf16(p0, p1);
        pk.y = cvtpk_bf16(p2, p3);
        *(u32x2*)&Pw[lr * 36 + tt * 8 + lg * 2] = pk;
      }
      __builtin_amdgcn_sched_barrier(0);
#pragma unroll
      for (int kk = 0; kk < 2; ++kk) {
        u32x4 pu = *(const u32x4*)&Pw[lr * 36 + kk * 16 + lg * 4];
        pf[qg][kk] = __builtin_bit_cast(s16x8, pu);
      }
      __builtin_amdgcn_sched_barrier(0);
    }

#pragma unroll
    for (int kk = 0; kk < 2; ++kk) {
      __builtin_amdgcn_s_setprio(1);
      o4[0] = MFMA16(pf[0][kk], ONES, o4[0]);
      o4[1] = MFMA16(pf[1][kk], ONES, o4[1]);
#pragma unroll
      for (int dt = 0; dt < 4; ++dt) {
        int vrow = dt * 16 + lr;
        s16x8 vf = *(const s16x8*)&Vb[vrow * 64 + ((((kk * 32 + lg * 8) >> 3) ^ (vrow & 7)) << 3)];
        o[0][dt] = MFMA16(pf[0][kk], vf, o[0][dt]);
        o[1][dt] = MFMA16(pf[1][kk], vf, o[1][dt]);
      }
      __builtin_amdgcn_s_setprio(0);
    }
    __syncthreads();
  }

#pragma unroll
  for (int qg = 0; qg < 2; ++qg) {
    f32x4 lq;
#pragma unroll
    for (int rr = 0; rr < 4; ++rr) lq[rr] = 1.f / o4[qg][rr];
    const size_t orow0 = (size_t)b * 1024 + qb + qg * 128 + w * 16;
#pragma unroll
    for (int dt = 0; dt < 4; ++dt)
#pragma unroll
      for (int rr = 0; rr < 4; ++rr)
        out[(orow0 + lg * 4 + rr) * 1024 + h * 64 + dt * 16 + lr] = f2b(o[qg][dt][rr] * lq[rr]);
  }
}

extern "C" void kernel_launch(void* const* d_in, const int* in_sizes, int n_in,
                              void* d_out, int out_size, void* d_ws, size_t ws_size,
                              hipStream_t stream) {
  const float* x = (const float*)d_in[0];
  const float* Wqkv = (const float*)d_in[1];
  const float* Wproj = (const float*)d_in[2];
  const float* bproj = (const float*)d_in[3];
  const float* A_k = (const float*)d_in[4];
  const float* B_k = (const float*)d_in[5];
  const float* A_v = (const float*)d_in[6];
  const float* B_v = (const float*)d_in[7];
  const int* task = (const int*)d_in[8];

  char* ws = (char*)d_ws;
  float* wk = (float*)ws;                                       // 4 MB
  float* wv = (float*)(ws + (4ull << 20));                      // 4 MB
  unsigned short* xb = (unsigned short*)(ws + (8ull << 20));    // 32 MB
  unsigned short* Wc = (unsigned short*)(ws + (40ull << 20));   // 6 MB
  unsigned short* Wp = (unsigned short*)(ws + (46ull << 20));   // 2 MB
  unsigned short* Qb = (unsigned short*)(ws + (48ull << 20));   // 32 MB (Kb = Qb+16M elems)
  unsigned short* Kb = (unsigned short*)(ws + (80ull << 20));   // 32 MB
  unsigned short* vT = (unsigned short*)(ws + (112ull << 20));  // 32 MB
  unsigned short* ao = (unsigned short*)(ws + (144ull << 20));  // 32 MB

  lora_and_cvt<<<17920, 256, 0, stream>>>(A_k, B_k, A_v, B_v, wk, wv, task, x, Wproj, xb, Wp);
  build_wc<<<3072, 256, 0, stream>>>(Wqkv, wk, wv, Wc);
  gemm256<1, 0, 1><<<dim3(12, 64), 512, 0, stream>>>(xb, Wc, Qb, nullptr, vT, 16384, 3072, 1024);
  attn_fwd<<<1024, 512, 0, stream>>>(Qb, Kb, vT, ao);
  gemm256<0, 1, 0><<<dim3(4, 64), 512, 0, stream>>>(ao, Wp, d_out, bproj, nullptr, 16384, 1024, 1024);
}